// Round 1
// baseline (1576.016 us; speedup 1.0000x reference)
//
#include <hip/hip_runtime.h>

#define N_NODES 50000
#define E_EDGES 800000
#define IN_DIM 256
#define HID 128
#define OUT_DIM 64

// h = relu(x @ W0 + b0). 8 rows per block, 128 threads (thread t owns column t).
__global__ __launch_bounds__(128) void k_lin(const float* __restrict__ x,
                                             const float* __restrict__ W0,
                                             const float* __restrict__ b0,
                                             float* __restrict__ h) {
    __shared__ float xs[8 * IN_DIM];
    const int t = threadIdx.x;
    const int row0 = blockIdx.x * 8;
    const float* xbase = x + (size_t)row0 * IN_DIM;
    #pragma unroll
    for (int i = 0; i < 16; ++i) xs[t + i * 128] = xbase[t + i * 128];
    __syncthreads();
    float acc[8];
    #pragma unroll
    for (int m = 0; m < 8; ++m) acc[m] = 0.f;
    for (int k = 0; k < IN_DIM; ++k) {
        float w = W0[k * HID + t];
        #pragma unroll
        for (int m = 0; m < 8; ++m) acc[m] += xs[m * IN_DIM + k] * w;
    }
    const float bias = b0[t];
    #pragma unroll
    for (int m = 0; m < 8; ++m) {
        float v = acc[m] + bias;
        h[(size_t)(row0 + m) * HID + t] = v > 0.f ? v : 0.f;
    }
}

// Per-node attention scores: sa[n]=dot(h[n],attw[0:128]), sb[n]=dot(h[n],attw[128:256]).
// One wave per node, 4 nodes per 256-thread block.
__global__ __launch_bounds__(256) void k_score(const float* __restrict__ h,
                                               const float* __restrict__ attw,
                                               float* __restrict__ sa,
                                               float* __restrict__ sb) {
    const int wave = threadIdx.x >> 6;
    const int lane = threadIdx.x & 63;
    const int n = blockIdx.x * 4 + wave;
    if (n >= N_NODES) return;
    const float* hr = h + (size_t)n * HID;
    float h0 = hr[lane], h1 = hr[lane + 64];
    float ps = h0 * attw[lane] + h1 * attw[lane + 64];
    float pd = h0 * attw[HID + lane] + h1 * attw[HID + lane + 64];
    #pragma unroll
    for (int off = 32; off > 0; off >>= 1) {
        ps += __shfl_down(ps, off);
        pd += __shfl_down(pd, off);
    }
    if (lane == 0) { sa[n] = ps; sb[n] = pd; }
}

// Edge pass: alpha = tanh(sa[row]+sb[col]+b); agg[col] += alpha * h[row].
// One wave per edge; lane l handles channels [2l, 2l+1].
__global__ __launch_bounds__(256) void k_edge(const float* __restrict__ h,
                                              const float* __restrict__ sa,
                                              const float* __restrict__ sb,
                                              const float* __restrict__ attb,
                                              const int* __restrict__ ei,
                                              float* __restrict__ agg) {
    const int wave = threadIdx.x >> 6;
    const int lane = threadIdx.x & 63;
    const int e = blockIdx.x * 4 + wave;
    if (e >= E_EDGES) return;
    const int row = ei[e];
    const int col = ei[E_EDGES + e];
    const float alpha = tanhf(sa[row] + sb[col] + attb[0]);
    const float2 v = ((const float2*)(h + (size_t)row * HID))[lane];
    float* d = agg + (size_t)col * HID + lane * 2;
    unsafeAtomicAdd(d,     alpha * v.x);
    unsafeAtomicAdd(d + 1, alpha * v.y);
}

// hout = relu(eps*hin + (1-eps)*agg), elementwise (hout may alias agg).
__global__ __launch_bounds__(256) void k_update(const float* __restrict__ hin,
                                                const float* __restrict__ agg,
                                                const float* __restrict__ epsp,
                                                float* __restrict__ hout) {
    const int i = blockIdx.x * 256 + threadIdx.x;
    const int total = N_NODES * HID / 4;
    if (i >= total) return;
    const float eps = epsp[0];
    const float om = 1.f - eps;
    float4 a = ((const float4*)hin)[i];
    float4 g = ((const float4*)agg)[i];
    float4 r;
    r.x = eps * a.x + om * g.x; r.x = r.x > 0.f ? r.x : 0.f;
    r.y = eps * a.y + om * g.y; r.y = r.y > 0.f ? r.y : 0.f;
    r.z = eps * a.z + om * g.z; r.z = r.z > 0.f ? r.z : 0.f;
    r.w = eps * a.w + om * g.w; r.w = r.w > 0.f ? r.w : 0.f;
    ((float4*)hout)[i] = r;
}

// out = h2 @ Wc + bc. 4 nodes per 256-thread block; thread (node=t>>6, o=t&63).
__global__ __launch_bounds__(256) void k_out(const float* __restrict__ h,
                                             const float* __restrict__ Wc,
                                             const float* __restrict__ bc,
                                             float* __restrict__ out) {
    __shared__ float hs[4 * HID];
    const int t = threadIdx.x;
    const int n0 = blockIdx.x * 4;
    const float* hbase = h + (size_t)n0 * HID;
    hs[t] = hbase[t];
    hs[t + 256] = hbase[t + 256];
    __syncthreads();
    const int local = t >> 6;
    const int o = t & 63;
    float acc = 0.f;
    #pragma unroll 8
    for (int k = 0; k < HID; ++k) acc += hs[local * HID + k] * Wc[k * OUT_DIM + o];
    out[(size_t)(n0 + local) * OUT_DIM + o] = acc + bc[o];
}

extern "C" void kernel_launch(void* const* d_in, const int* in_sizes, int n_in,
                              void* d_out, int out_size, void* d_ws, size_t ws_size,
                              hipStream_t stream) {
    const float* x   = (const float*)d_in[0];
    const int*   ei  = (const int*)d_in[1];
    const float* W0  = (const float*)d_in[2];
    const float* b0  = (const float*)d_in[3];
    const float* aw1 = (const float*)d_in[4];
    const float* ab1 = (const float*)d_in[5];
    const float* e1  = (const float*)d_in[6];
    const float* aw2 = (const float*)d_in[7];
    const float* ab2 = (const float*)d_in[8];
    const float* e2  = (const float*)d_in[9];
    const float* Wc  = (const float*)d_in[10];
    const float* bc  = (const float*)d_in[11];
    float* out = (float*)d_out;

    float* A  = (float*)d_ws;                       // N*HID
    float* B  = A + (size_t)N_NODES * HID;          // N*HID
    float* sa = B + (size_t)N_NODES * HID;          // N
    float* sb = sa + N_NODES;                       // N

    const size_t hbytes = (size_t)N_NODES * HID * sizeof(float);

    // h0 = relu(x@W0+b0) -> A
    k_lin<<<N_NODES / 8, 128, 0, stream>>>(x, W0, b0, A);
    // layer 1
    k_score<<<(N_NODES + 3) / 4, 256, 0, stream>>>(A, aw1, sa, sb);
    hipMemsetAsync(B, 0, hbytes, stream);
    k_edge<<<E_EDGES / 4, 256, 0, stream>>>(A, sa, sb, ab1, ei, B);
    k_update<<<(N_NODES * HID / 4) / 256, 256, 0, stream>>>(A, B, e1, B);  // h1 -> B
    // layer 2
    k_score<<<(N_NODES + 3) / 4, 256, 0, stream>>>(B, aw2, sa, sb);
    hipMemsetAsync(A, 0, hbytes, stream);
    k_edge<<<E_EDGES / 4, 256, 0, stream>>>(B, sa, sb, ab2, ei, A);
    k_update<<<(N_NODES * HID / 4) / 256, 256, 0, stream>>>(B, A, e2, A);  // h2 -> A
    // out = h2 @ Wc + bc
    k_out<<<N_NODES / 4, 256, 0, stream>>>(A, Wc, bc, out);
}

// Round 2
// 504.667 us; speedup vs baseline: 3.1229x; 3.1229x over previous
//
#include <hip/hip_runtime.h>

#define N_NODES 50000
#define E_EDGES 800000
#define IN_DIM 256
#define HID 128
#define OUT_DIM 64

// ---------- CSR construction (by destination col) ----------

__global__ __launch_bounds__(256) void k_hist(const int* __restrict__ ei,
                                              int* __restrict__ cnt) {
    const int e = blockIdx.x * 256 + threadIdx.x;
    if (e < E_EDGES) atomicAdd(&cnt[ei[E_EDGES + e]], 1);
}

// Single-block exclusive scan over cnt[0..N) -> ptr[0..N], plus mutable copy cur.
__global__ __launch_bounds__(1024) void k_scan(const int* __restrict__ cnt,
                                               int* __restrict__ ptr,
                                               int* __restrict__ cur) {
    __shared__ int wtot[16];
    __shared__ int wexc[16];
    const int t = threadIdx.x;
    const int lane = t & 63;
    const int wid = t >> 6;
    int carry = 0;
    for (int base = 0; base < N_NODES; base += 1024) {
        const int i = base + t;
        int v = (i < N_NODES) ? cnt[i] : 0;
        const int orig = v;
        #pragma unroll
        for (int off = 1; off < 64; off <<= 1) {
            int y = __shfl_up(v, off);
            if (lane >= off) v += y;
        }
        if (lane == 63) wtot[wid] = v;
        __syncthreads();
        if (wid == 0 && lane < 16) {
            int w = wtot[lane];
            #pragma unroll
            for (int off = 1; off < 16; off <<= 1) {
                int y = __shfl_up(w, off);
                if (lane >= off) w += y;
            }
            wexc[lane] = w - wtot[lane];  // exclusive prefix of wave totals
        }
        __syncthreads();
        const int total = wexc[15] + wtot[15];
        if (i < N_NODES) {
            const int ex = carry + wexc[wid] + (v - orig);
            ptr[i] = ex;
            cur[i] = ex;
        }
        carry += total;
        __syncthreads();  // protect wtot/wexc before next chunk
    }
    if (t == 0) ptr[N_NODES] = carry;
}

__global__ __launch_bounds__(256) void k_scatter(const int* __restrict__ ei,
                                                 int* __restrict__ cur,
                                                 int* __restrict__ srcidx) {
    const int e = blockIdx.x * 256 + threadIdx.x;
    if (e >= E_EDGES) return;
    const int row = ei[e];
    const int col = ei[E_EDGES + e];
    const int pos = atomicAdd(&cur[col], 1);
    srcidx[pos] = row;
}

// ---------- dense kernels ----------

// h = relu(x @ W0 + b0). 8 rows per block, 128 threads (thread t owns column t).
__global__ __launch_bounds__(128) void k_lin(const float* __restrict__ x,
                                             const float* __restrict__ W0,
                                             const float* __restrict__ b0,
                                             float* __restrict__ h) {
    __shared__ float xs[8 * IN_DIM];
    const int t = threadIdx.x;
    const int row0 = blockIdx.x * 8;
    const float* xbase = x + (size_t)row0 * IN_DIM;
    #pragma unroll
    for (int i = 0; i < 16; ++i) xs[t + i * 128] = xbase[t + i * 128];
    __syncthreads();
    float acc[8];
    #pragma unroll
    for (int m = 0; m < 8; ++m) acc[m] = 0.f;
    for (int k = 0; k < IN_DIM; ++k) {
        float w = W0[k * HID + t];
        #pragma unroll
        for (int m = 0; m < 8; ++m) acc[m] += xs[m * IN_DIM + k] * w;
    }
    const float bias = b0[t];
    #pragma unroll
    for (int m = 0; m < 8; ++m) {
        float v = acc[m] + bias;
        h[(size_t)(row0 + m) * HID + t] = v > 0.f ? v : 0.f;
    }
}

// Per-node attention scores for layer 1: sa[n]=dot(h[n],attw[0:128]), sb[n]=dot(h[n],attw[128:256]).
__global__ __launch_bounds__(256) void k_score(const float* __restrict__ h,
                                               const float* __restrict__ attw,
                                               float* __restrict__ sa,
                                               float* __restrict__ sb) {
    const int wave = threadIdx.x >> 6;
    const int lane = threadIdx.x & 63;
    const int n = blockIdx.x * 4 + wave;
    if (n >= N_NODES) return;
    const float* hr = h + (size_t)n * HID;
    float h0 = hr[lane], h1 = hr[lane + 64];
    float ps = h0 * attw[lane] + h1 * attw[lane + 64];
    float pd = h0 * attw[HID + lane] + h1 * attw[HID + lane + 64];
    #pragma unroll
    for (int off = 32; off > 0; off >>= 1) {
        ps += __shfl_down(ps, off);
        pd += __shfl_down(pd, off);
    }
    if (lane == 0) { sa[n] = ps; sb[n] = pd; }
}

// CSR aggregation + eps-mix + relu, fused with next-layer score computation.
// One wave per destination node; half-waves process 2 edges concurrently
// (lane = half*32+sub; sub owns channels 4*sub..4*sub+3 as float4).
__global__ __launch_bounds__(256) void k_agg(const float* __restrict__ hin,
                                             const float* __restrict__ sa,
                                             const float* __restrict__ sb,
                                             const float* __restrict__ attb,
                                             const float* __restrict__ epsp,
                                             const int* __restrict__ ptr,
                                             const int* __restrict__ srcidx,
                                             float* __restrict__ hout,
                                             const float* __restrict__ attw_next,
                                             float* __restrict__ sa_next,
                                             float* __restrict__ sb_next) {
    const int wid = threadIdx.x >> 6;
    const int lane = threadIdx.x & 63;
    const int n = blockIdx.x * 4 + wid;
    if (n >= N_NODES) return;
    const int half = lane >> 5;
    const int sub = lane & 31;
    const float b = attb[0];
    const float sbn = sb[n];
    const int beg = ptr[n];
    const int end = ptr[n + 1];
    float4 acc = {0.f, 0.f, 0.f, 0.f};
    for (int e = beg + half; e < end; e += 2) {
        const int src = srcidx[e];
        const float alpha = tanhf(sa[src] + sbn + b);
        const float4 v = ((const float4*)(hin + (size_t)src * HID))[sub];
        acc.x += alpha * v.x;
        acc.y += alpha * v.y;
        acc.z += alpha * v.z;
        acc.w += alpha * v.w;
    }
    // combine the two half-wave partial sums (same channels, different edges)
    acc.x += __shfl_xor(acc.x, 32);
    acc.y += __shfl_xor(acc.y, 32);
    acc.z += __shfl_xor(acc.z, 32);
    acc.w += __shfl_xor(acc.w, 32);

    const float eps = epsp[0];
    const float om = 1.f - eps;
    float4 hv = {0.f, 0.f, 0.f, 0.f};
    if (half == 0) {
        const float4 hi = ((const float4*)(hin + (size_t)n * HID))[sub];
        hv.x = fmaxf(eps * hi.x + om * acc.x, 0.f);
        hv.y = fmaxf(eps * hi.y + om * acc.y, 0.f);
        hv.z = fmaxf(eps * hi.z + om * acc.z, 0.f);
        hv.w = fmaxf(eps * hi.w + om * acc.w, 0.f);
        ((float4*)(hout + (size_t)n * HID))[sub] = hv;
    }
    if (attw_next != nullptr) {
        float ps = 0.f, pd = 0.f;
        if (half == 0) {
            const float4 w1 = ((const float4*)attw_next)[sub];
            const float4 w2 = ((const float4*)(attw_next + HID))[sub];
            ps = hv.x * w1.x + hv.y * w1.y + hv.z * w1.z + hv.w * w1.w;
            pd = hv.x * w2.x + hv.y * w2.y + hv.z * w2.z + hv.w * w2.w;
        }
        #pragma unroll
        for (int off = 16; off > 0; off >>= 1) {
            ps += __shfl_down(ps, off);
            pd += __shfl_down(pd, off);
        }
        if (lane == 0) { sa_next[n] = ps; sb_next[n] = pd; }
    }
}

// out = h2 @ Wc + bc. 4 nodes per 256-thread block; thread (node=t>>6, o=t&63).
__global__ __launch_bounds__(256) void k_out(const float* __restrict__ h,
                                             const float* __restrict__ Wc,
                                             const float* __restrict__ bc,
                                             float* __restrict__ out) {
    __shared__ float hs[4 * HID];
    const int t = threadIdx.x;
    const int n0 = blockIdx.x * 4;
    const float* hbase = h + (size_t)n0 * HID;
    hs[t] = hbase[t];
    hs[t + 256] = hbase[t + 256];
    __syncthreads();
    const int local = t >> 6;
    const int o = t & 63;
    float acc = 0.f;
    #pragma unroll 8
    for (int k = 0; k < HID; ++k) acc += hs[local * HID + k] * Wc[k * OUT_DIM + o];
    out[(size_t)(n0 + local) * OUT_DIM + o] = acc + bc[o];
}

extern "C" void kernel_launch(void* const* d_in, const int* in_sizes, int n_in,
                              void* d_out, int out_size, void* d_ws, size_t ws_size,
                              hipStream_t stream) {
    const float* x   = (const float*)d_in[0];
    const int*   ei  = (const int*)d_in[1];
    const float* W0  = (const float*)d_in[2];
    const float* b0  = (const float*)d_in[3];
    const float* aw1 = (const float*)d_in[4];
    const float* ab1 = (const float*)d_in[5];
    const float* e1  = (const float*)d_in[6];
    const float* aw2 = (const float*)d_in[7];
    const float* ab2 = (const float*)d_in[8];
    const float* e2  = (const float*)d_in[9];
    const float* Wc  = (const float*)d_in[10];
    const float* bc  = (const float*)d_in[11];
    float* out = (float*)d_out;

    // workspace layout (floats/ints, 4 B each)
    float* A   = (float*)d_ws;                        // N*HID
    float* B   = A + (size_t)N_NODES * HID;           // N*HID
    float* sa1 = B + (size_t)N_NODES * HID;           // N
    float* sb1 = sa1 + N_NODES;                       // N
    float* sa2 = sb1 + N_NODES;                       // N
    float* sb2 = sa2 + N_NODES;                       // N
    int* cnt    = (int*)(sb2 + N_NODES);              // N
    int* ptr    = cnt + N_NODES;                      // N+1
    int* cur    = ptr + N_NODES + 1;                  // N
    int* srcidx = cur + N_NODES;                      // E

    // ---- CSR build (reused by both layers) ----
    hipMemsetAsync(cnt, 0, N_NODES * sizeof(int), stream);
    k_hist<<<(E_EDGES + 255) / 256, 256, 0, stream>>>(ei, cnt);
    k_scan<<<1, 1024, 0, stream>>>(cnt, ptr, cur);
    k_scatter<<<(E_EDGES + 255) / 256, 256, 0, stream>>>(ei, cur, srcidx);

    // ---- h0 = relu(x@W0+b0) -> A ----
    k_lin<<<N_NODES / 8, 128, 0, stream>>>(x, W0, b0, A);
    // ---- layer-1 scores ----
    k_score<<<(N_NODES + 3) / 4, 256, 0, stream>>>(A, aw1, sa1, sb1);
    // ---- layer 1: A -> B (also produces layer-2 scores) ----
    k_agg<<<(N_NODES + 3) / 4, 256, 0, stream>>>(A, sa1, sb1, ab1, e1, ptr, srcidx,
                                                 B, aw2, sa2, sb2);
    // ---- layer 2: B -> A ----
    k_agg<<<(N_NODES + 3) / 4, 256, 0, stream>>>(B, sa2, sb2, ab2, e2, ptr, srcidx,
                                                 A, nullptr, nullptr, nullptr);
    // ---- out = h2 @ Wc + bc ----
    k_out<<<N_NODES / 4, 256, 0, stream>>>(A, Wc, bc, out);
}

// Round 3
// 362.521 us; speedup vs baseline: 4.3474x; 1.3921x over previous
//
#include <hip/hip_runtime.h>

#define N_NODES 50000
#define E_EDGES 800000
#define IN_DIM 256
#define HID 128
#define OUT_DIM 64

typedef unsigned short u16;
typedef __attribute__((ext_vector_type(8))) short short8;
typedef __attribute__((ext_vector_type(4))) float floatx4;

__device__ __forceinline__ u16 f2bf(float f) {
    unsigned u = __float_as_uint(f);
    unsigned r = (u + 0x7FFFu + ((u >> 16) & 1u)) >> 16;  // RNE
    return (u16)r;
}
__device__ __forceinline__ void bf8_unpack(uint4 v, float* f) {
    f[0] = __uint_as_float(v.x << 16); f[1] = __uint_as_float(v.x & 0xffff0000u);
    f[2] = __uint_as_float(v.y << 16); f[3] = __uint_as_float(v.y & 0xffff0000u);
    f[4] = __uint_as_float(v.z << 16); f[5] = __uint_as_float(v.z & 0xffff0000u);
    f[6] = __uint_as_float(v.w << 16); f[7] = __uint_as_float(v.w & 0xffff0000u);
}
__device__ __forceinline__ uint4 bf8_pack(const float* f) {
    uint4 o;
    o.x = f2bf(f[0]) | ((unsigned)f2bf(f[1]) << 16);
    o.y = f2bf(f[2]) | ((unsigned)f2bf(f[3]) << 16);
    o.z = f2bf(f[4]) | ((unsigned)f2bf(f[5]) << 16);
    o.w = f2bf(f[6]) | ((unsigned)f2bf(f[7]) << 16);
    return o;
}

// ---------- W0 transpose + bf16 convert: Wt[n][k] = bf16(W0[k][n]) ----------
__global__ __launch_bounds__(256) void k_wt(const float* __restrict__ W0,
                                            u16* __restrict__ Wt) {
    const int t = blockIdx.x * 256 + threadIdx.x;  // 32768
    const int n = t >> 8, k = t & 255;
    Wt[t] = f2bf(W0[k * HID + n]);
}

// ---------- CSR construction (by destination col) ----------
__global__ __launch_bounds__(256) void k_hist(const int* __restrict__ ei,
                                              int* __restrict__ cnt) {
    const int e = blockIdx.x * 256 + threadIdx.x;
    if (e < E_EDGES) atomicAdd(&cnt[ei[E_EDGES + e]], 1);
}

__global__ __launch_bounds__(1024) void k_scanA(const int* __restrict__ cnt,
                                                int* __restrict__ ptr,
                                                int* __restrict__ btot) {
    __shared__ int wtot[16];
    __shared__ int wexc[16];
    const int t = threadIdx.x;
    const int lane = t & 63;
    const int wd = t >> 6;
    const int i = blockIdx.x * 1024 + t;
    int v = (i < N_NODES) ? cnt[i] : 0;
    const int orig = v;
    #pragma unroll
    for (int off = 1; off < 64; off <<= 1) {
        int y = __shfl_up(v, off);
        if (lane >= off) v += y;
    }
    if (lane == 63) wtot[wd] = v;
    __syncthreads();
    if (t < 16) {
        int w = wtot[t];
        #pragma unroll
        for (int off = 1; off < 16; off <<= 1) {
            int y = __shfl_up(w, off);
            if (t >= off) w += y;
        }
        wexc[t] = w - wtot[t];
    }
    __syncthreads();
    if (i < N_NODES) ptr[i] = wexc[wd] + (v - orig);
    if (t == 0) btot[blockIdx.x] = wexc[15] + wtot[15];
}

__global__ __launch_bounds__(64) void k_scanB(int* __restrict__ btot,
                                              int* __restrict__ ptr) {
    const int t = threadIdx.x;
    int v = (t < 49) ? btot[t] : 0;
    const int orig = v;
    #pragma unroll
    for (int off = 1; off < 64; off <<= 1) {
        int y = __shfl_up(v, off);
        if (t >= off) v += y;
    }
    if (t < 49) btot[t] = v - orig;  // single wave: all loads precede stores
    if (t == 0) ptr[N_NODES] = E_EDGES;
}

__global__ __launch_bounds__(1024) void k_scanC(int* __restrict__ ptr,
                                                int* __restrict__ cur,
                                                const int* __restrict__ btot) {
    const int i = blockIdx.x * 1024 + threadIdx.x;
    if (i < N_NODES) {
        const int p = ptr[i] + btot[blockIdx.x];
        ptr[i] = p;
        cur[i] = p;
    }
}

__global__ __launch_bounds__(256) void k_scatter(const int* __restrict__ ei,
                                                 int* __restrict__ cur,
                                                 int* __restrict__ srcidx) {
    const int e = blockIdx.x * 256 + threadIdx.x;
    if (e >= E_EDGES) return;
    const int row = ei[e];
    const int col = ei[E_EDGES + e];
    const int pos = atomicAdd(&cur[col], 1);
    srcidx[pos] = row;
}

// ---------- h0 = relu(x@W0+b0) via MFMA, + layer-1 scores fused ----------
// 128 rows/block, 256 threads (4 waves, wave w owns rows 32w..32w+31).
// K staged in 64-wide slices; bf16 operands; fp32 accumulate.
#define LROWS 128
#define KS 64
#define KP 72  // 64 + 8 pad (keeps 16B alignment, breaks pow2 bank stride)

__global__ __launch_bounds__(256) void k_lin_mfma(
    const float* __restrict__ x, const u16* __restrict__ Wt,
    const float* __restrict__ b0, const float* __restrict__ aw1,
    u16* __restrict__ h, float* __restrict__ sa, float* __restrict__ sb) {
    __shared__ u16 As[LROWS][KP];  // 18432 B
    __shared__ u16 Bs[HID][KP];    // 18432 B
    const int t = threadIdx.x;
    const int lane = t & 63;
    const int w = t >> 6;
    const int sub = lane & 15;
    const int quad = lane >> 4;
    const int row0 = blockIdx.x * LROWS;

    floatx4 acc0[8], acc1[8];
    #pragma unroll
    for (int i = 0; i < 8; ++i) {
        acc0[i] = (floatx4){0.f, 0.f, 0.f, 0.f};
        acc1[i] = (floatx4){0.f, 0.f, 0.f, 0.f};
    }

    const int sr = t >> 1;         // staging row (A) / n (B)
    const int sk = (t & 1) * 32;   // k offset within slice

    for (int k0 = 0; k0 < IN_DIM; k0 += KS) {
        // stage A: 128 rows x 64 k, fp32 -> bf16
        {
            int gr = row0 + sr;
            if (gr > N_NODES - 1) gr = N_NODES - 1;
            const float* src = x + (size_t)gr * IN_DIM + k0 + sk;
            #pragma unroll
            for (int i = 0; i < 4; ++i) {
                float4 f0 = ((const float4*)src)[2 * i];
                float4 f1 = ((const float4*)src)[2 * i + 1];
                uint4 p;
                p.x = f2bf(f0.x) | ((unsigned)f2bf(f0.y) << 16);
                p.y = f2bf(f0.z) | ((unsigned)f2bf(f0.w) << 16);
                p.z = f2bf(f1.x) | ((unsigned)f2bf(f1.y) << 16);
                p.w = f2bf(f1.z) | ((unsigned)f2bf(f1.w) << 16);
                *(uint4*)&As[sr][sk + 8 * i] = p;
            }
            // stage B: 128 n x 64 k bf16 from pre-transposed Wt
            const u16* wsrc = Wt + sr * IN_DIM + k0 + sk;
            #pragma unroll
            for (int i = 0; i < 4; ++i)
                *(uint4*)&Bs[sr][sk + 8 * i] = ((const uint4*)wsrc)[i];
        }
        __syncthreads();
        #pragma unroll
        for (int kk = 0; kk < KS; kk += 32) {
            short8 a0 = *(const short8*)&As[w * 32 + sub][kk + quad * 8];
            short8 a1 = *(const short8*)&As[w * 32 + 16 + sub][kk + quad * 8];
            #pragma unroll
            for (int ct = 0; ct < 8; ++ct) {
                short8 bb = *(const short8*)&Bs[ct * 16 + sub][kk + quad * 8];
                acc0[ct] = __builtin_amdgcn_mfma_f32_16x16x32_bf16(a0, bb, acc0[ct], 0, 0, 0);
                acc1[ct] = __builtin_amdgcn_mfma_f32_16x16x32_bf16(a1, bb, acc1[ct], 0, 0, 0);
            }
        }
        __syncthreads();
    }

    // epilogue: bias + relu + bf16 store; fused layer-1 scores
    float bias[8], w1c[8], w2c[8];
    #pragma unroll
    for (int ct = 0; ct < 8; ++ct) {
        const int col = ct * 16 + sub;
        bias[ct] = b0[col];
        w1c[ct] = aw1[col];
        w2c[ct] = aw1[HID + col];
    }
    float ps[2][4], pd[2][4];
    #pragma unroll
    for (int i = 0; i < 2; ++i)
        #pragma unroll
        for (int j = 0; j < 4; ++j) { ps[i][j] = 0.f; pd[i][j] = 0.f; }

    #pragma unroll
    for (int tile = 0; tile < 2; ++tile) {
        #pragma unroll
        for (int reg = 0; reg < 4; ++reg) {
            const int gr = row0 + w * 32 + tile * 16 + quad * 4 + reg;
            const bool ok = gr < N_NODES;
            #pragma unroll
            for (int ct = 0; ct < 8; ++ct) {
                floatx4 v = tile ? acc1[ct] : acc0[ct];
                const float val = fmaxf(v[reg] + bias[ct], 0.f);
                if (ok) h[(size_t)gr * HID + ct * 16 + sub] = f2bf(val);
                ps[tile][reg] += val * w1c[ct];
                pd[tile][reg] += val * w2c[ct];
            }
        }
    }
    #pragma unroll
    for (int tile = 0; tile < 2; ++tile) {
        #pragma unroll
        for (int reg = 0; reg < 4; ++reg) {
            float a = ps[tile][reg], d = pd[tile][reg];
            #pragma unroll
            for (int off = 1; off < 16; off <<= 1) {
                a += __shfl_xor(a, off);
                d += __shfl_xor(d, off);
            }
            if (sub == 0) {
                const int gr = row0 + w * 32 + tile * 16 + quad * 4 + reg;
                if (gr < N_NODES) { sa[gr] = a; sb[gr] = d; }
            }
        }
    }
}

// ---------- CSR aggregation (bf16 h) + eps-mix + relu + next-layer scores ----
// One wave per node; quarter-wave (16 lanes) per edge, 4 edges in flight.
// Lane = q*16+sub; sub owns channels 8*sub..8*sub+7 (one 16B load).
__global__ __launch_bounds__(256) void k_agg(const u16* __restrict__ hin,
                                             const float* __restrict__ sa,
                                             const float* __restrict__ sb,
                                             const float* __restrict__ attb,
                                             const float* __restrict__ epsp,
                                             const int* __restrict__ ptr,
                                             const int* __restrict__ srcidx,
                                             u16* __restrict__ hout,
                                             const float* __restrict__ attw_next,
                                             float* __restrict__ sa_next,
                                             float* __restrict__ sb_next) {
    const int wid = threadIdx.x >> 6;
    const int lane = threadIdx.x & 63;
    const int n = blockIdx.x * 4 + wid;
    if (n >= N_NODES) return;
    const int q = lane >> 4;
    const int sub = lane & 15;
    const float b = attb[0];
    const float sbn = sb[n];
    const int beg = ptr[n];
    const int end = ptr[n + 1];
    float acc[8];
    #pragma unroll
    for (int j = 0; j < 8; ++j) acc[j] = 0.f;

    for (int e = beg + q; e < end; e += 4) {
        const int src = srcidx[e];
        const float alpha = tanhf(sa[src] + sbn + b);
        const uint4 v = *(const uint4*)(hin + (size_t)src * HID + sub * 8);
        float f[8];
        bf8_unpack(v, f);
        #pragma unroll
        for (int j = 0; j < 8; ++j) acc[j] += alpha * f[j];
    }
    // combine the 4 quarter-wave partials (same channels, different edges)
    #pragma unroll
    for (int j = 0; j < 8; ++j) {
        acc[j] += __shfl_xor(acc[j], 16);
        acc[j] += __shfl_xor(acc[j], 32);
    }

    if (q == 0) {
        const float eps = epsp[0];
        const float om = 1.f - eps;
        const uint4 sv = *(const uint4*)(hin + (size_t)n * HID + sub * 8);
        float self[8], hv[8];
        bf8_unpack(sv, self);
        #pragma unroll
        for (int j = 0; j < 8; ++j)
            hv[j] = fmaxf(eps * self[j] + om * acc[j], 0.f);
        *(uint4*)(hout + (size_t)n * HID + sub * 8) = bf8_pack(hv);

        if (attw_next != nullptr) {
            float psum = 0.f, dsum = 0.f;
            #pragma unroll
            for (int j = 0; j < 8; ++j) {
                psum += hv[j] * attw_next[sub * 8 + j];
                dsum += hv[j] * attw_next[HID + sub * 8 + j];
            }
            #pragma unroll
            for (int off = 1; off < 16; off <<= 1) {
                psum += __shfl_xor(psum, off);
                dsum += __shfl_xor(dsum, off);
            }
            if (sub == 0) { sa_next[n] = psum; sb_next[n] = dsum; }
        }
    }
}

// ---------- out = h2 @ Wc + bc (h2 in bf16) ----------
__global__ __launch_bounds__(256) void k_out(const u16* __restrict__ h,
                                             const float* __restrict__ Wc,
                                             const float* __restrict__ bc,
                                             float* __restrict__ out) {
    __shared__ float hs[4 * HID];
    const int t = threadIdx.x;
    const int n0 = blockIdx.x * 4;
    const unsigned wv = ((const unsigned*)(h + (size_t)n0 * HID))[t];
    hs[2 * t]     = __uint_as_float(wv << 16);
    hs[2 * t + 1] = __uint_as_float(wv & 0xffff0000u);
    __syncthreads();
    const int local = t >> 6;
    const int o = t & 63;
    float acc = 0.f;
    #pragma unroll 8
    for (int k = 0; k < HID; ++k) acc += hs[local * HID + k] * Wc[k * OUT_DIM + o];
    out[(size_t)(n0 + local) * OUT_DIM + o] = acc + bc[o];
}

extern "C" void kernel_launch(void* const* d_in, const int* in_sizes, int n_in,
                              void* d_out, int out_size, void* d_ws, size_t ws_size,
                              hipStream_t stream) {
    const float* x   = (const float*)d_in[0];
    const int*   ei  = (const int*)d_in[1];
    const float* W0  = (const float*)d_in[2];
    const float* b0  = (const float*)d_in[3];
    const float* aw1 = (const float*)d_in[4];
    const float* ab1 = (const float*)d_in[5];
    const float* e1  = (const float*)d_in[6];
    const float* aw2 = (const float*)d_in[7];
    const float* ab2 = (const float*)d_in[8];
    const float* e2  = (const float*)d_in[9];
    const float* Wc  = (const float*)d_in[10];
    const float* bc  = (const float*)d_in[11];
    float* out = (float*)d_out;

    // workspace layout
    u16* hA = (u16*)d_ws;                              // N*HID bf16
    u16* hB = hA + (size_t)N_NODES * HID;              // N*HID bf16
    u16* Wt = hB + (size_t)N_NODES * HID;              // 128*256 bf16
    float* sa1 = (float*)(Wt + IN_DIM * HID);          // N
    float* sb1 = sa1 + N_NODES;
    float* sa2 = sb1 + N_NODES;
    float* sb2 = sa2 + N_NODES;
    int* cnt    = (int*)(sb2 + N_NODES);               // N
    int* ptr    = cnt + N_NODES;                       // N+1
    int* cur    = ptr + N_NODES + 1;                   // N
    int* srcidx = cur + N_NODES;                       // E
    int* btot   = srcidx + E_EDGES;                    // 64

    // ---- CSR build ----
    hipMemsetAsync(cnt, 0, N_NODES * sizeof(int), stream);
    k_wt<<<IN_DIM * HID / 256, 256, 0, stream>>>(W0, Wt);
    k_hist<<<(E_EDGES + 255) / 256, 256, 0, stream>>>(ei, cnt);
    k_scanA<<<(N_NODES + 1023) / 1024, 1024, 0, stream>>>(cnt, ptr, btot);
    k_scanB<<<1, 64, 0, stream>>>(btot, ptr);
    k_scanC<<<(N_NODES + 1023) / 1024, 1024, 0, stream>>>(ptr, cur, btot);
    k_scatter<<<(E_EDGES + 255) / 256, 256, 0, stream>>>(ei, cur, srcidx);

    // ---- h0 = relu(x@W0+b0) -> hA (bf16), + layer-1 scores ----
    k_lin_mfma<<<(N_NODES + LROWS - 1) / LROWS, 256, 0, stream>>>(x, Wt, b0, aw1,
                                                                  hA, sa1, sb1);
    // ---- layer 1: hA -> hB (+ layer-2 scores) ----
    k_agg<<<(N_NODES + 3) / 4, 256, 0, stream>>>(hA, sa1, sb1, ab1, e1, ptr, srcidx,
                                                 hB, aw2, sa2, sb2);
    // ---- layer 2: hB -> hA ----
    k_agg<<<(N_NODES + 3) / 4, 256, 0, stream>>>(hB, sa2, sb2, ab2, e2, ptr, srcidx,
                                                 hA, nullptr, nullptr, nullptr);
    // ---- out = h2 @ Wc + bc ----
    k_out<<<N_NODES / 4, 256, 0, stream>>>(hA, Wc, bc, out);
}

// Round 4
// 313.506 us; speedup vs baseline: 5.0271x; 1.1563x over previous
//
#include <hip/hip_runtime.h>

#define N_NODES 50000
#define E_EDGES 800000
#define IN_DIM 256
#define HID 128
#define OUT_DIM 64

typedef unsigned short u16;
typedef __attribute__((ext_vector_type(8))) short short8;
typedef __attribute__((ext_vector_type(4))) float floatx4;

__device__ __forceinline__ u16 f2bf(float f) {
    unsigned u = __float_as_uint(f);
    unsigned r = (u + 0x7FFFu + ((u >> 16) & 1u)) >> 16;  // RNE
    return (u16)r;
}
__device__ __forceinline__ void bf8_unpack(uint4 v, float* f) {
    f[0] = __uint_as_float(v.x << 16); f[1] = __uint_as_float(v.x & 0xffff0000u);
    f[2] = __uint_as_float(v.y << 16); f[3] = __uint_as_float(v.y & 0xffff0000u);
    f[4] = __uint_as_float(v.z << 16); f[5] = __uint_as_float(v.z & 0xffff0000u);
    f[6] = __uint_as_float(v.w << 16); f[7] = __uint_as_float(v.w & 0xffff0000u);
}
__device__ __forceinline__ uint4 bf8_pack(const float* f) {
    uint4 o;
    o.x = f2bf(f[0]) | ((unsigned)f2bf(f[1]) << 16);
    o.y = f2bf(f[2]) | ((unsigned)f2bf(f[3]) << 16);
    o.z = f2bf(f[4]) | ((unsigned)f2bf(f[5]) << 16);
    o.w = f2bf(f[6]) | ((unsigned)f2bf(f[7]) << 16);
    return o;
}

// ---------- fused prep: dest histogram (4 edges/thread) + W0^T bf16 + Wc^T bf16
__global__ __launch_bounds__(256) void k_prep(const int* __restrict__ ei,
                                              int* __restrict__ cnt,
                                              const float* __restrict__ W0,
                                              u16* __restrict__ Wt,
                                              const float* __restrict__ Wc,
                                              u16* __restrict__ Wct) {
    const int gid = blockIdx.x * 256 + threadIdx.x;
    if (gid < E_EDGES / 4) {
        const int4 cols = ((const int4*)(ei + E_EDGES))[gid];
        atomicAdd(&cnt[cols.x], 1);
        atomicAdd(&cnt[cols.y], 1);
        atomicAdd(&cnt[cols.z], 1);
        atomicAdd(&cnt[cols.w], 1);
    }
    if (gid < IN_DIM * HID) {  // Wt[n][k] = bf16(W0[k][n])
        Wt[gid] = f2bf(W0[(gid & 255) * HID + (gid >> 8)]);
    }
    if (gid < HID * OUT_DIM) {  // Wct[n][k] = bf16(Wc[k][n])
        Wct[gid] = f2bf(Wc[(gid & 127) * OUT_DIM + (gid >> 7)]);
    }
}

// ---------- scan (3-phase) ----------
__global__ __launch_bounds__(1024) void k_scanA(const int* __restrict__ cnt,
                                                int* __restrict__ ptr,
                                                int* __restrict__ btot) {
    __shared__ int wtot[16];
    __shared__ int wexc[16];
    const int t = threadIdx.x;
    const int lane = t & 63;
    const int wd = t >> 6;
    const int i = blockIdx.x * 1024 + t;
    int v = (i < N_NODES) ? cnt[i] : 0;
    const int orig = v;
    #pragma unroll
    for (int off = 1; off < 64; off <<= 1) {
        int y = __shfl_up(v, off);
        if (lane >= off) v += y;
    }
    if (lane == 63) wtot[wd] = v;
    __syncthreads();
    if (t < 16) {
        int w = wtot[t];
        #pragma unroll
        for (int off = 1; off < 16; off <<= 1) {
            int y = __shfl_up(w, off);
            if (t >= off) w += y;
        }
        wexc[t] = w - wtot[t];
    }
    __syncthreads();
    if (i < N_NODES) ptr[i] = wexc[wd] + (v - orig);
    if (t == 0) btot[blockIdx.x] = wexc[15] + wtot[15];
}

__global__ __launch_bounds__(64) void k_scanB(int* __restrict__ btot,
                                              int* __restrict__ ptr) {
    const int t = threadIdx.x;
    int v = (t < 49) ? btot[t] : 0;
    const int orig = v;
    #pragma unroll
    for (int off = 1; off < 64; off <<= 1) {
        int y = __shfl_up(v, off);
        if (t >= off) v += y;
    }
    if (t < 49) btot[t] = v - orig;  // single wave: all loads precede stores
    if (t == 0) ptr[N_NODES] = E_EDGES;
}

__global__ __launch_bounds__(1024) void k_scanC(int* __restrict__ ptr,
                                                int* __restrict__ cur,
                                                const int* __restrict__ btot) {
    const int i = blockIdx.x * 1024 + threadIdx.x;
    if (i < N_NODES) {
        const int p = ptr[i] + btot[blockIdx.x];
        ptr[i] = p;
        cur[i] = p;
    }
}

// ---------- scatter: 4 edges/thread (4 independent atomic->store chains) ----
__global__ __launch_bounds__(256) void k_scatter(const int* __restrict__ ei,
                                                 int* __restrict__ cur,
                                                 int* __restrict__ srcidx) {
    const int gid = blockIdx.x * 256 + threadIdx.x;
    if (gid >= E_EDGES / 4) return;
    const int4 rows = ((const int4*)ei)[gid];
    const int4 cols = ((const int4*)(ei + E_EDGES))[gid];
    const int p0 = atomicAdd(&cur[cols.x], 1);
    const int p1 = atomicAdd(&cur[cols.y], 1);
    const int p2 = atomicAdd(&cur[cols.z], 1);
    const int p3 = atomicAdd(&cur[cols.w], 1);
    srcidx[p0] = rows.x;
    srcidx[p1] = rows.y;
    srcidx[p2] = rows.z;
    srcidx[p3] = rows.w;
}

// ---------- h0 = relu(x@W0+b0) via MFMA, + layer-1 scores fused ----------
#define LROWS 128
#define KS 64
#define KP 72  // 64 + 8 pad

__global__ __launch_bounds__(256) void k_lin_mfma(
    const float* __restrict__ x, const u16* __restrict__ Wt,
    const float* __restrict__ b0, const float* __restrict__ aw1,
    u16* __restrict__ h, float* __restrict__ sa, float* __restrict__ sb) {
    __shared__ u16 As[LROWS][KP];
    __shared__ u16 Bs[HID][KP];
    const int t = threadIdx.x;
    const int lane = t & 63;
    const int w = t >> 6;
    const int sub = lane & 15;
    const int quad = lane >> 4;
    const int row0 = blockIdx.x * LROWS;

    floatx4 acc0[8], acc1[8];
    #pragma unroll
    for (int i = 0; i < 8; ++i) {
        acc0[i] = (floatx4){0.f, 0.f, 0.f, 0.f};
        acc1[i] = (floatx4){0.f, 0.f, 0.f, 0.f};
    }

    const int sr = t >> 1;
    const int sk = (t & 1) * 32;

    for (int k0 = 0; k0 < IN_DIM; k0 += KS) {
        {
            int gr = row0 + sr;
            if (gr > N_NODES - 1) gr = N_NODES - 1;
            const float* src = x + (size_t)gr * IN_DIM + k0 + sk;
            #pragma unroll
            for (int i = 0; i < 4; ++i) {
                float4 f0 = ((const float4*)src)[2 * i];
                float4 f1 = ((const float4*)src)[2 * i + 1];
                uint4 p;
                p.x = f2bf(f0.x) | ((unsigned)f2bf(f0.y) << 16);
                p.y = f2bf(f0.z) | ((unsigned)f2bf(f0.w) << 16);
                p.z = f2bf(f1.x) | ((unsigned)f2bf(f1.y) << 16);
                p.w = f2bf(f1.z) | ((unsigned)f2bf(f1.w) << 16);
                *(uint4*)&As[sr][sk + 8 * i] = p;
            }
            const u16* wsrc = Wt + sr * IN_DIM + k0 + sk;
            #pragma unroll
            for (int i = 0; i < 4; ++i)
                *(uint4*)&Bs[sr][sk + 8 * i] = ((const uint4*)wsrc)[i];
        }
        __syncthreads();
        #pragma unroll
        for (int kk = 0; kk < KS; kk += 32) {
            short8 a0 = *(const short8*)&As[w * 32 + sub][kk + quad * 8];
            short8 a1 = *(const short8*)&As[w * 32 + 16 + sub][kk + quad * 8];
            #pragma unroll
            for (int ct = 0; ct < 8; ++ct) {
                short8 bb = *(const short8*)&Bs[ct * 16 + sub][kk + quad * 8];
                acc0[ct] = __builtin_amdgcn_mfma_f32_16x16x32_bf16(a0, bb, acc0[ct], 0, 0, 0);
                acc1[ct] = __builtin_amdgcn_mfma_f32_16x16x32_bf16(a1, bb, acc1[ct], 0, 0, 0);
            }
        }
        __syncthreads();
    }

    float bias[8], w1c[8], w2c[8];
    #pragma unroll
    for (int ct = 0; ct < 8; ++ct) {
        const int col = ct * 16 + sub;
        bias[ct] = b0[col];
        w1c[ct] = aw1[col];
        w2c[ct] = aw1[HID + col];
    }
    float ps[2][4], pd[2][4];
    #pragma unroll
    for (int i = 0; i < 2; ++i)
        #pragma unroll
        for (int j = 0; j < 4; ++j) { ps[i][j] = 0.f; pd[i][j] = 0.f; }

    #pragma unroll
    for (int tile = 0; tile < 2; ++tile) {
        #pragma unroll
        for (int reg = 0; reg < 4; ++reg) {
            const int gr = row0 + w * 32 + tile * 16 + quad * 4 + reg;
            const bool ok = gr < N_NODES;
            #pragma unroll
            for (int ct = 0; ct < 8; ++ct) {
                floatx4 v = tile ? acc1[ct] : acc0[ct];
                const float val = fmaxf(v[reg] + bias[ct], 0.f);
                if (ok) h[(size_t)gr * HID + ct * 16 + sub] = f2bf(val);
                ps[tile][reg] += val * w1c[ct];
                pd[tile][reg] += val * w2c[ct];
            }
        }
    }
    #pragma unroll
    for (int tile = 0; tile < 2; ++tile) {
        #pragma unroll
        for (int reg = 0; reg < 4; ++reg) {
            float a = ps[tile][reg], d = pd[tile][reg];
            #pragma unroll
            for (int off = 1; off < 16; off <<= 1) {
                a += __shfl_xor(a, off);
                d += __shfl_xor(d, off);
            }
            if (sub == 0) {
                const int gr = row0 + w * 32 + tile * 16 + quad * 4 + reg;
                if (gr < N_NODES) { sa[gr] = a; sb[gr] = d; }
            }
        }
    }
}

// ---------- CSR aggregation (bf16 h) + eps-mix + relu + next-layer scores ----
__global__ __launch_bounds__(256) void k_agg(const u16* __restrict__ hin,
                                             const float* __restrict__ sa,
                                             const float* __restrict__ sb,
                                             const float* __restrict__ attb,
                                             const float* __restrict__ epsp,
                                             const int* __restrict__ ptr,
                                             const int* __restrict__ srcidx,
                                             u16* __restrict__ hout,
                                             const float* __restrict__ attw_next,
                                             float* __restrict__ sa_next,
                                             float* __restrict__ sb_next) {
    const int wid = threadIdx.x >> 6;
    const int lane = threadIdx.x & 63;
    const int n = blockIdx.x * 4 + wid;
    if (n >= N_NODES) return;
    const int q = lane >> 4;
    const int sub = lane & 15;
    const float b = attb[0];
    const float sbn = sb[n];
    const int beg = ptr[n];
    const int end = ptr[n + 1];
    float acc[8];
    #pragma unroll
    for (int j = 0; j < 8; ++j) acc[j] = 0.f;

    for (int e = beg + q; e < end; e += 4) {
        const int src = srcidx[e];
        const float alpha = tanhf(sa[src] + sbn + b);
        const uint4 v = *(const uint4*)(hin + (size_t)src * HID + sub * 8);
        float f[8];
        bf8_unpack(v, f);
        #pragma unroll
        for (int j = 0; j < 8; ++j) acc[j] += alpha * f[j];
    }
    #pragma unroll
    for (int j = 0; j < 8; ++j) {
        acc[j] += __shfl_xor(acc[j], 16);
        acc[j] += __shfl_xor(acc[j], 32);
    }

    if (q == 0) {
        const float eps = epsp[0];
        const float om = 1.f - eps;
        const uint4 sv = *(const uint4*)(hin + (size_t)n * HID + sub * 8);
        float self[8], hv[8];
        bf8_unpack(sv, self);
        #pragma unroll
        for (int j = 0; j < 8; ++j)
            hv[j] = fmaxf(eps * self[j] + om * acc[j], 0.f);
        *(uint4*)(hout + (size_t)n * HID + sub * 8) = bf8_pack(hv);

        if (attw_next != nullptr) {
            float psum = 0.f, dsum = 0.f;
            #pragma unroll
            for (int j = 0; j < 8; ++j) {
                psum += hv[j] * attw_next[sub * 8 + j];
                dsum += hv[j] * attw_next[HID + sub * 8 + j];
            }
            #pragma unroll
            for (int off = 1; off < 16; off <<= 1) {
                psum += __shfl_xor(psum, off);
                dsum += __shfl_xor(dsum, off);
            }
            if (sub == 0) { sa_next[n] = psum; sb_next[n] = dsum; }
        }
    }
}

// ---------- out = h2 @ Wc + bc via MFMA (h bf16, Wct bf16 pre-transposed) ----
// 128 rows/block, 4 waves; wave w owns rows w*32..w*32+31; 4 col-tiles of 16.
__global__ __launch_bounds__(256) void k_out_mfma(const u16* __restrict__ h,
                                                  const u16* __restrict__ Wct,
                                                  const float* __restrict__ bc,
                                                  float* __restrict__ out) {
    const int t = threadIdx.x;
    const int lane = t & 63;
    const int w = t >> 6;
    const int sub = lane & 15;
    const int quad = lane >> 4;
    const int row0 = blockIdx.x * 128 + w * 32;

    floatx4 acc[2][4];
    #pragma unroll
    for (int i = 0; i < 2; ++i)
        #pragma unroll
        for (int j = 0; j < 4; ++j) acc[i][j] = (floatx4){0.f, 0.f, 0.f, 0.f};

    int r0 = row0 + sub;      if (r0 > N_NODES - 1) r0 = N_NODES - 1;
    int r1 = row0 + 16 + sub; if (r1 > N_NODES - 1) r1 = N_NODES - 1;

    #pragma unroll
    for (int ks = 0; ks < 4; ++ks) {
        const int ko = ks * 32 + quad * 8;
        short8 a0 = *(const short8*)(h + (size_t)r0 * HID + ko);
        short8 a1 = *(const short8*)(h + (size_t)r1 * HID + ko);
        #pragma unroll
        for (int ct = 0; ct < 4; ++ct) {
            short8 bb = *(const short8*)(Wct + (ct * 16 + sub) * HID + ko);
            acc[0][ct] = __builtin_amdgcn_mfma_f32_16x16x32_bf16(a0, bb, acc[0][ct], 0, 0, 0);
            acc[1][ct] = __builtin_amdgcn_mfma_f32_16x16x32_bf16(a1, bb, acc[1][ct], 0, 0, 0);
        }
    }

    #pragma unroll
    for (int ct = 0; ct < 4; ++ct) {
        const float bias = bc[ct * 16 + sub];
        #pragma unroll
        for (int tile = 0; tile < 2; ++tile) {
            #pragma unroll
            for (int reg = 0; reg < 4; ++reg) {
                const int gr = row0 + tile * 16 + quad * 4 + reg;
                if (gr < N_NODES)
                    out[(size_t)gr * OUT_DIM + ct * 16 + sub] = acc[tile][ct][reg] + bias;
            }
        }
    }
}

extern "C" void kernel_launch(void* const* d_in, const int* in_sizes, int n_in,
                              void* d_out, int out_size, void* d_ws, size_t ws_size,
                              hipStream_t stream) {
    const float* x   = (const float*)d_in[0];
    const int*   ei  = (const int*)d_in[1];
    const float* W0  = (const float*)d_in[2];
    const float* b0  = (const float*)d_in[3];
    const float* aw1 = (const float*)d_in[4];
    const float* ab1 = (const float*)d_in[5];
    const float* e1  = (const float*)d_in[6];
    const float* aw2 = (const float*)d_in[7];
    const float* ab2 = (const float*)d_in[8];
    const float* e2  = (const float*)d_in[9];
    const float* Wc  = (const float*)d_in[10];
    const float* bc  = (const float*)d_in[11];
    float* out = (float*)d_out;

    // workspace layout
    u16* hA  = (u16*)d_ws;                             // N*HID bf16
    u16* hB  = hA + (size_t)N_NODES * HID;             // N*HID bf16
    u16* Wt  = hB + (size_t)N_NODES * HID;             // 128*256 bf16
    u16* Wct = Wt + IN_DIM * HID;                      // 64*128 bf16
    float* sa1 = (float*)(Wct + HID * OUT_DIM);        // N
    float* sb1 = sa1 + N_NODES;
    float* sa2 = sb1 + N_NODES;
    float* sb2 = sa2 + N_NODES;
    int* cnt    = (int*)(sb2 + N_NODES);               // N
    int* ptr    = cnt + N_NODES;                       // N+1
    int* cur    = ptr + N_NODES + 1;                   // N
    int* srcidx = cur + N_NODES;                       // E
    int* btot   = srcidx + E_EDGES;                    // 64

    hipMemsetAsync(cnt, 0, N_NODES * sizeof(int), stream);
    k_prep<<<(E_EDGES / 4 + 255) / 256, 256, 0, stream>>>(ei, cnt, W0, Wt, Wc, Wct);
    k_scanA<<<(N_NODES + 1023) / 1024, 1024, 0, stream>>>(cnt, ptr, btot);
    k_scanB<<<1, 64, 0, stream>>>(btot, ptr);
    k_scanC<<<(N_NODES + 1023) / 1024, 1024, 0, stream>>>(ptr, cur, btot);
    k_scatter<<<(E_EDGES / 4 + 255) / 256, 256, 0, stream>>>(ei, cur, srcidx);

    k_lin_mfma<<<(N_NODES + LROWS - 1) / LROWS, 256, 0, stream>>>(x, Wt, b0, aw1,
                                                                  hA, sa1, sb1);
    k_agg<<<(N_NODES + 3) / 4, 256, 0, stream>>>(hA, sa1, sb1, ab1, e1, ptr, srcidx,
                                                 hB, aw2, sa2, sb2);
    k_agg<<<(N_NODES + 3) / 4, 256, 0, stream>>>(hB, sa2, sb2, ab2, e2, ptr, srcidx,
                                                 hA, nullptr, nullptr, nullptr);
    k_out_mfma<<<(N_NODES + 127) / 128, 256, 0, stream>>>(hA, Wct, bc, out);
}

// Round 6
// 297.753 us; speedup vs baseline: 5.2930x; 1.0529x over previous
//
#include <hip/hip_runtime.h>

#define N_NODES 50000
#define E_EDGES 800000
#define IN_DIM 256
#define HID 128
#define OUT_DIM 64

typedef unsigned short u16;
typedef __attribute__((ext_vector_type(8))) short short8;
typedef __attribute__((ext_vector_type(4))) float floatx4;

__device__ __forceinline__ u16 f2bf(float f) {
    unsigned u = __float_as_uint(f);
    unsigned r = (u + 0x7FFFu + ((u >> 16) & 1u)) >> 16;  // RNE
    return (u16)r;
}
__device__ __forceinline__ void bf8_unpack(uint4 v, float* f) {
    f[0] = __uint_as_float(v.x << 16); f[1] = __uint_as_float(v.x & 0xffff0000u);
    f[2] = __uint_as_float(v.y << 16); f[3] = __uint_as_float(v.y & 0xffff0000u);
    f[4] = __uint_as_float(v.z << 16); f[5] = __uint_as_float(v.z & 0xffff0000u);
    f[6] = __uint_as_float(v.w << 16); f[7] = __uint_as_float(v.w & 0xffff0000u);
}
__device__ __forceinline__ uint4 bf8_pack(const float* f) {
    uint4 o;
    o.x = f2bf(f[0]) | ((unsigned)f2bf(f[1]) << 16);
    o.y = f2bf(f[2]) | ((unsigned)f2bf(f[3]) << 16);
    o.z = f2bf(f[4]) | ((unsigned)f2bf(f[5]) << 16);
    o.w = f2bf(f[6]) | ((unsigned)f2bf(f[7]) << 16);
    return o;
}

// ---------- fused prep: dest histogram (4 edges/thread) + W0^T bf16 + Wc^T bf16
__global__ __launch_bounds__(256) void k_prep(const int* __restrict__ ei,
                                              int* __restrict__ cnt,
                                              const float* __restrict__ W0,
                                              u16* __restrict__ Wt,
                                              const float* __restrict__ Wc,
                                              u16* __restrict__ Wct) {
    const int gid = blockIdx.x * 256 + threadIdx.x;
    if (gid < E_EDGES / 4) {
        const int4 cols = ((const int4*)(ei + E_EDGES))[gid];
        atomicAdd(&cnt[cols.x], 1);
        atomicAdd(&cnt[cols.y], 1);
        atomicAdd(&cnt[cols.z], 1);
        atomicAdd(&cnt[cols.w], 1);
    }
    if (gid < IN_DIM * HID) {  // Wt[n][k] = bf16(W0[k][n])
        Wt[gid] = f2bf(W0[(gid & 255) * HID + (gid >> 8)]);
    }
    if (gid < HID * OUT_DIM) {  // Wct[n][k] = bf16(Wc[k][n])
        Wct[gid] = f2bf(Wc[(gid & 127) * OUT_DIM + (gid >> 7)]);
    }
}

// ---------- scan (3-phase) ----------
__global__ __launch_bounds__(1024) void k_scanA(const int* __restrict__ cnt,
                                                int* __restrict__ ptr,
                                                int* __restrict__ btot) {
    __shared__ int wtot[16];
    __shared__ int wexc[16];
    const int t = threadIdx.x;
    const int lane = t & 63;
    const int wd = t >> 6;
    const int i = blockIdx.x * 1024 + t;
    int v = (i < N_NODES) ? cnt[i] : 0;
    const int orig = v;
    #pragma unroll
    for (int off = 1; off < 64; off <<= 1) {
        int y = __shfl_up(v, off);
        if (lane >= off) v += y;
    }
    if (lane == 63) wtot[wd] = v;
    __syncthreads();
    if (t < 16) {
        int w = wtot[t];
        #pragma unroll
        for (int off = 1; off < 16; off <<= 1) {
            int y = __shfl_up(w, off);
            if (t >= off) w += y;
        }
        wexc[t] = w - wtot[t];
    }
    __syncthreads();
    if (i < N_NODES) ptr[i] = wexc[wd] + (v - orig);
    if (t == 0) btot[blockIdx.x] = wexc[15] + wtot[15];
}

__global__ __launch_bounds__(64) void k_scanB(int* __restrict__ btot,
                                              int* __restrict__ ptr) {
    const int t = threadIdx.x;
    int v = (t < 49) ? btot[t] : 0;
    const int orig = v;
    #pragma unroll
    for (int off = 1; off < 64; off <<= 1) {
        int y = __shfl_up(v, off);
        if (t >= off) v += y;
    }
    if (t < 49) btot[t] = v - orig;  // single wave: all loads precede stores
    if (t == 0) ptr[N_NODES] = E_EDGES;
}

__global__ __launch_bounds__(1024) void k_scanC(int* __restrict__ ptr,
                                                int* __restrict__ cur,
                                                const int* __restrict__ btot) {
    const int i = blockIdx.x * 1024 + threadIdx.x;
    if (i < N_NODES) {
        const int p = ptr[i] + btot[blockIdx.x];
        ptr[i] = p;
        cur[i] = p;
    }
}

// ---------- scatter: 4 edges/thread (4 independent atomic->store chains) ----
__global__ __launch_bounds__(256) void k_scatter(const int* __restrict__ ei,
                                                 int* __restrict__ cur,
                                                 int* __restrict__ srcidx) {
    const int gid = blockIdx.x * 256 + threadIdx.x;
    if (gid >= E_EDGES / 4) return;
    const int4 rows = ((const int4*)ei)[gid];
    const int4 cols = ((const int4*)(ei + E_EDGES))[gid];
    const int p0 = atomicAdd(&cur[cols.x], 1);
    const int p1 = atomicAdd(&cur[cols.y], 1);
    const int p2 = atomicAdd(&cur[cols.z], 1);
    const int p3 = atomicAdd(&cur[cols.w], 1);
    srcidx[p0] = rows.x;
    srcidx[p1] = rows.y;
    srcidx[p2] = rows.z;
    srcidx[p3] = rows.w;
}

// ---------- h0 = relu(x@W0+b0) via MFMA, + layer-1 scores fused ----------
#define LROWS 128
#define KS 64
#define KP 72  // 64 + 8 pad

__global__ __launch_bounds__(256) void k_lin_mfma(
    const float* __restrict__ x, const u16* __restrict__ Wt,
    const float* __restrict__ b0, const float* __restrict__ aw1,
    u16* __restrict__ h, float* __restrict__ sa, float* __restrict__ sb) {
    __shared__ u16 As[LROWS][KP];
    __shared__ u16 Bs[HID][KP];
    const int t = threadIdx.x;
    const int lane = t & 63;
    const int w = t >> 6;
    const int sub = lane & 15;
    const int quad = lane >> 4;
    const int row0 = blockIdx.x * LROWS;

    floatx4 acc0[8], acc1[8];
    #pragma unroll
    for (int i = 0; i < 8; ++i) {
        acc0[i] = (floatx4){0.f, 0.f, 0.f, 0.f};
        acc1[i] = (floatx4){0.f, 0.f, 0.f, 0.f};
    }

    const int sr = t >> 1;
    const int sk = (t & 1) * 32;

    for (int k0 = 0; k0 < IN_DIM; k0 += KS) {
        {
            int gr = row0 + sr;
            if (gr > N_NODES - 1) gr = N_NODES - 1;
            const float* src = x + (size_t)gr * IN_DIM + k0 + sk;
            #pragma unroll
            for (int i = 0; i < 4; ++i) {
                float4 f0 = ((const float4*)src)[2 * i];
                float4 f1 = ((const float4*)src)[2 * i + 1];
                uint4 p;
                p.x = f2bf(f0.x) | ((unsigned)f2bf(f0.y) << 16);
                p.y = f2bf(f0.z) | ((unsigned)f2bf(f0.w) << 16);
                p.z = f2bf(f1.x) | ((unsigned)f2bf(f1.y) << 16);
                p.w = f2bf(f1.z) | ((unsigned)f2bf(f1.w) << 16);
                *(uint4*)&As[sr][sk + 8 * i] = p;
            }
            const u16* wsrc = Wt + sr * IN_DIM + k0 + sk;
            #pragma unroll
            for (int i = 0; i < 4; ++i)
                *(uint4*)&Bs[sr][sk + 8 * i] = ((const uint4*)wsrc)[i];
        }
        __syncthreads();
        #pragma unroll
        for (int kk = 0; kk < KS; kk += 32) {
            short8 a0 = *(const short8*)&As[w * 32 + sub][kk + quad * 8];
            short8 a1 = *(const short8*)&As[w * 32 + 16 + sub][kk + quad * 8];
            #pragma unroll
            for (int ct = 0; ct < 8; ++ct) {
                short8 bb = *(const short8*)&Bs[ct * 16 + sub][kk + quad * 8];
                acc0[ct] = __builtin_amdgcn_mfma_f32_16x16x32_bf16(a0, bb, acc0[ct], 0, 0, 0);
                acc1[ct] = __builtin_amdgcn_mfma_f32_16x16x32_bf16(a1, bb, acc1[ct], 0, 0, 0);
            }
        }
        __syncthreads();
    }

    float bias[8], w1c[8], w2c[8];
    #pragma unroll
    for (int ct = 0; ct < 8; ++ct) {
        const int col = ct * 16 + sub;
        bias[ct] = b0[col];
        w1c[ct] = aw1[col];
        w2c[ct] = aw1[HID + col];
    }
    float ps[2][4], pd[2][4];
    #pragma unroll
    for (int i = 0; i < 2; ++i)
        #pragma unroll
        for (int j = 0; j < 4; ++j) { ps[i][j] = 0.f; pd[i][j] = 0.f; }

    #pragma unroll
    for (int tile = 0; tile < 2; ++tile) {
        #pragma unroll
        for (int reg = 0; reg < 4; ++reg) {
            const int gr = row0 + w * 32 + tile * 16 + quad * 4 + reg;
            const bool ok = gr < N_NODES;
            #pragma unroll
            for (int ct = 0; ct < 8; ++ct) {
                floatx4 v = tile ? acc1[ct] : acc0[ct];
                const float val = fmaxf(v[reg] + bias[ct], 0.f);
                if (ok) h[(size_t)gr * HID + ct * 16 + sub] = f2bf(val);
                ps[tile][reg] += val * w1c[ct];
                pd[tile][reg] += val * w2c[ct];
            }
        }
    }
    #pragma unroll
    for (int tile = 0; tile < 2; ++tile) {
        #pragma unroll
        for (int reg = 0; reg < 4; ++reg) {
            float a = ps[tile][reg], d = pd[tile][reg];
            #pragma unroll
            for (int off = 1; off < 16; off <<= 1) {
                a += __shfl_xor(a, off);
                d += __shfl_xor(d, off);
            }
            if (sub == 0) {
                const int gr = row0 + w * 32 + tile * 16 + quad * 4 + reg;
                if (gr < N_NODES) { sa[gr] = a; sb[gr] = d; }
            }
        }
    }
}

// ---------- CSR aggregation (bf16 h) + eps-mix + relu + next-layer scores ----
// One QUARTER-WAVE (16 lanes) per node; lane sub owns channels 8*sub..8*sub+7.
// Inner loop unrolled 4 edges -> 16 independent gathers in flight per wave.
__global__ __launch_bounds__(256) void k_agg(const u16* __restrict__ hin,
                                             const float* __restrict__ sa,
                                             const float* __restrict__ sb,
                                             const float* __restrict__ attb,
                                             const float* __restrict__ epsp,
                                             const int* __restrict__ ptr,
                                             const int* __restrict__ srcidx,
                                             u16* __restrict__ hout,
                                             const float* __restrict__ attw_next,
                                             float* __restrict__ sa_next,
                                             float* __restrict__ sb_next) {
    const int qid = threadIdx.x >> 4;   // 16 quarter-waves per block
    const int sub = threadIdx.x & 15;
    const int n = blockIdx.x * 16 + qid;
    if (n >= N_NODES) return;
    const float b = attb[0];
    const float sbn = sb[n];
    const int beg = ptr[n];
    const int end = ptr[n + 1];
    float acc[8];
    #pragma unroll
    for (int j = 0; j < 8; ++j) acc[j] = 0.f;

    int e = beg;
    for (; e + 4 <= end; e += 4) {
        const int s0 = srcidx[e];
        const int s1 = srcidx[e + 1];
        const int s2 = srcidx[e + 2];
        const int s3 = srcidx[e + 3];
        const uint4 v0 = *(const uint4*)(hin + (size_t)s0 * HID + sub * 8);
        const uint4 v1 = *(const uint4*)(hin + (size_t)s1 * HID + sub * 8);
        const uint4 v2 = *(const uint4*)(hin + (size_t)s2 * HID + sub * 8);
        const uint4 v3 = *(const uint4*)(hin + (size_t)s3 * HID + sub * 8);
        const float a0 = tanhf(sa[s0] + sbn + b);
        const float a1 = tanhf(sa[s1] + sbn + b);
        const float a2 = tanhf(sa[s2] + sbn + b);
        const float a3 = tanhf(sa[s3] + sbn + b);
        float f0[8], f1[8], f2[8], f3[8];
        bf8_unpack(v0, f0);
        bf8_unpack(v1, f1);
        bf8_unpack(v2, f2);
        bf8_unpack(v3, f3);
        #pragma unroll
        for (int j = 0; j < 8; ++j)
            acc[j] += a0 * f0[j] + a1 * f1[j] + a2 * f2[j] + a3 * f3[j];
    }
    for (; e < end; ++e) {
        const int s = srcidx[e];
        const float a = tanhf(sa[s] + sbn + b);
        const uint4 v = *(const uint4*)(hin + (size_t)s * HID + sub * 8);
        float f[8];
        bf8_unpack(v, f);
        #pragma unroll
        for (int j = 0; j < 8; ++j) acc[j] += a * f[j];
    }

    const float eps = epsp[0];
    const float om = 1.f - eps;
    const uint4 sv = *(const uint4*)(hin + (size_t)n * HID + sub * 8);
    float self[8], hv[8];
    bf8_unpack(sv, self);
    #pragma unroll
    for (int j = 0; j < 8; ++j)
        hv[j] = fmaxf(eps * self[j] + om * acc[j], 0.f);
    *(uint4*)(hout + (size_t)n * HID + sub * 8) = bf8_pack(hv);

    if (attw_next != nullptr) {
        float psum = 0.f, dsum = 0.f;
        #pragma unroll
        for (int j = 0; j < 8; ++j) {
            psum += hv[j] * attw_next[sub * 8 + j];
            dsum += hv[j] * attw_next[HID + sub * 8 + j];
        }
        #pragma unroll
        for (int off = 1; off < 16; off <<= 1) {
            psum += __shfl_xor(psum, off);
            dsum += __shfl_xor(dsum, off);
        }
        if (sub == 0) { sa_next[n] = psum; sb_next[n] = dsum; }
    }
}

// ---------- out = h2 @ Wc + bc via MFMA (h bf16, Wct bf16 pre-transposed) ----
__global__ __launch_bounds__(256) void k_out_mfma(const u16* __restrict__ h,
                                                  const u16* __restrict__ Wct,
                                                  const float* __restrict__ bc,
                                                  float* __restrict__ out) {
    const int t = threadIdx.x;
    const int lane = t & 63;
    const int w = t >> 6;
    const int sub = lane & 15;
    const int quad = lane >> 4;
    const int row0 = blockIdx.x * 128 + w * 32;

    floatx4 acc[2][4];
    #pragma unroll
    for (int i = 0; i < 2; ++i)
        #pragma unroll
        for (int j = 0; j < 4; ++j) acc[i][j] = (floatx4){0.f, 0.f, 0.f, 0.f};

    int r0 = row0 + sub;      if (r0 > N_NODES - 1) r0 = N_NODES - 1;
    int r1 = row0 + 16 + sub; if (r1 > N_NODES - 1) r1 = N_NODES - 1;

    #pragma unroll
    for (int ks = 0; ks < 4; ++ks) {
        const int ko = ks * 32 + quad * 8;
        short8 a0 = *(const short8*)(h + (size_t)r0 * HID + ko);
        short8 a1 = *(const short8*)(h + (size_t)r1 * HID + ko);
        #pragma unroll
        for (int ct = 0; ct < 4; ++ct) {
            short8 bb = *(const short8*)(Wct + (ct * 16 + sub) * HID + ko);
            acc[0][ct] = __builtin_amdgcn_mfma_f32_16x16x32_bf16(a0, bb, acc[0][ct], 0, 0, 0);
            acc[1][ct] = __builtin_amdgcn_mfma_f32_16x16x32_bf16(a1, bb, acc[1][ct], 0, 0, 0);
        }
    }

    #pragma unroll
    for (int ct = 0; ct < 4; ++ct) {
        const float bias = bc[ct * 16 + sub];
        #pragma unroll
        for (int tile = 0; tile < 2; ++tile) {
            #pragma unroll
            for (int reg = 0; reg < 4; ++reg) {
                const int gr = row0 + tile * 16 + quad * 4 + reg;
                if (gr < N_NODES)
                    out[(size_t)gr * OUT_DIM + ct * 16 + sub] = acc[tile][ct][reg] + bias;
            }
        }
    }
}

extern "C" void kernel_launch(void* const* d_in, const int* in_sizes, int n_in,
                              void* d_out, int out_size, void* d_ws, size_t ws_size,
                              hipStream_t stream) {
    const float* x   = (const float*)d_in[0];
    const int*   ei  = (const int*)d_in[1];
    const float* W0  = (const float*)d_in[2];
    const float* b0  = (const float*)d_in[3];
    const float* aw1 = (const float*)d_in[4];
    const float* ab1 = (const float*)d_in[5];
    const float* e1  = (const float*)d_in[6];
    const float* aw2 = (const float*)d_in[7];
    const float* ab2 = (const float*)d_in[8];
    const float* e2  = (const float*)d_in[9];
    const float* Wc  = (const float*)d_in[10];
    const float* bc  = (const float*)d_in[11];
    float* out = (float*)d_out;

    // workspace layout
    u16* hA  = (u16*)d_ws;                             // N*HID bf16
    u16* hB  = hA + (size_t)N_NODES * HID;             // N*HID bf16
    u16* Wt  = hB + (size_t)N_NODES * HID;             // 128*256 bf16
    u16* Wct = Wt + IN_DIM * HID;                      // 64*128 bf16
    float* sa1 = (float*)(Wct + HID * OUT_DIM);        // N
    float* sb1 = sa1 + N_NODES;
    float* sa2 = sb1 + N_NODES;
    float* sb2 = sa2 + N_NODES;
    int* cnt    = (int*)(sb2 + N_NODES);               // N
    int* ptr    = cnt + N_NODES;                       // N+1
    int* cur    = ptr + N_NODES + 1;                   // N
    int* srcidx = cur + N_NODES;                       // E
    int* btot   = srcidx + E_EDGES;                    // 64

    hipMemsetAsync(cnt, 0, N_NODES * sizeof(int), stream);
    k_prep<<<(E_EDGES / 4 + 255) / 256, 256, 0, stream>>>(ei, cnt, W0, Wt, Wc, Wct);
    k_scanA<<<(N_NODES + 1023) / 1024, 1024, 0, stream>>>(cnt, ptr, btot);
    k_scanB<<<1, 64, 0, stream>>>(btot, ptr);
    k_scanC<<<(N_NODES + 1023) / 1024, 1024, 0, stream>>>(ptr, cur, btot);
    k_scatter<<<(E_EDGES / 4 + 255) / 256, 256, 0, stream>>>(ei, cur, srcidx);

    k_lin_mfma<<<(N_NODES + LROWS - 1) / LROWS, 256, 0, stream>>>(x, Wt, b0, aw1,
                                                                  hA, sa1, sb1);
    k_agg<<<(N_NODES + 15) / 16, 256, 0, stream>>>(hA, sa1, sb1, ab1, e1, ptr, srcidx,
                                                   hB, aw2, sa2, sb2);
    k_agg<<<(N_NODES + 15) / 16, 256, 0, stream>>>(hB, sa2, sb2, ab2, e2, ptr, srcidx,
                                                   hA, nullptr, nullptr, nullptr);
    k_out_mfma<<<(N_NODES + 127) / 128, 256, 0, stream>>>(hA, Wct, bc, out);
}

// Round 7
// 288.016 us; speedup vs baseline: 5.4720x; 1.0338x over previous
//
#include <hip/hip_runtime.h>

#define N_NODES 50000
#define E_EDGES 800000
#define IN_DIM 256
#define HID 128
#define OUT_DIM 64

typedef unsigned short u16;
typedef __attribute__((ext_vector_type(8))) short short8;
typedef __attribute__((ext_vector_type(4))) float floatx4;

__device__ __forceinline__ u16 f2bf(float f) {
    unsigned u = __float_as_uint(f);
    unsigned r = (u + 0x7FFFu + ((u >> 16) & 1u)) >> 16;  // RNE
    return (u16)r;
}
__device__ __forceinline__ void bf8_unpack(uint4 v, float* f) {
    f[0] = __uint_as_float(v.x << 16); f[1] = __uint_as_float(v.x & 0xffff0000u);
    f[2] = __uint_as_float(v.y << 16); f[3] = __uint_as_float(v.y & 0xffff0000u);
    f[4] = __uint_as_float(v.z << 16); f[5] = __uint_as_float(v.z & 0xffff0000u);
    f[6] = __uint_as_float(v.w << 16); f[7] = __uint_as_float(v.w & 0xffff0000u);
}
__device__ __forceinline__ uint4 bf8_pack(const float* f) {
    uint4 o;
    o.x = f2bf(f[0]) | ((unsigned)f2bf(f[1]) << 16);
    o.y = f2bf(f[2]) | ((unsigned)f2bf(f[3]) << 16);
    o.z = f2bf(f[4]) | ((unsigned)f2bf(f[5]) << 16);
    o.w = f2bf(f[6]) | ((unsigned)f2bf(f[7]) << 16);
    return o;
}

// ---------- fused prep: hist+rank (8 edges/thread) + W0^T bf16 + Wc^T bf16 ----
__global__ __launch_bounds__(256) void k_prep(const int* __restrict__ ei,
                                              int* __restrict__ cnt,
                                              int* __restrict__ rank,
                                              const float* __restrict__ W0,
                                              u16* __restrict__ Wt,
                                              const float* __restrict__ Wc,
                                              u16* __restrict__ Wct) {
    const int gid = blockIdx.x * 256 + threadIdx.x;
    if (gid < E_EDGES / 8) {
        const int4 c0 = ((const int4*)(ei + E_EDGES))[2 * gid];
        const int4 c1 = ((const int4*)(ei + E_EDGES))[2 * gid + 1];
        int4 r0, r1;
        r0.x = atomicAdd(&cnt[c0.x], 1);
        r0.y = atomicAdd(&cnt[c0.y], 1);
        r0.z = atomicAdd(&cnt[c0.z], 1);
        r0.w = atomicAdd(&cnt[c0.w], 1);
        r1.x = atomicAdd(&cnt[c1.x], 1);
        r1.y = atomicAdd(&cnt[c1.y], 1);
        r1.z = atomicAdd(&cnt[c1.z], 1);
        r1.w = atomicAdd(&cnt[c1.w], 1);
        ((int4*)rank)[2 * gid] = r0;
        ((int4*)rank)[2 * gid + 1] = r1;
    }
    if (gid < IN_DIM * HID) {  // Wt[n][k] = bf16(W0[k][n])
        Wt[gid] = f2bf(W0[(gid & 255) * HID + (gid >> 8)]);
    }
    if (gid < HID * OUT_DIM) {  // Wct[n][k] = bf16(Wc[k][n])
        Wct[gid] = f2bf(Wc[(gid & 127) * OUT_DIM + (gid >> 7)]);
    }
}

// ---------- scan (3-phase) ----------
__global__ __launch_bounds__(1024) void k_scanA(const int* __restrict__ cnt,
                                                int* __restrict__ ptr,
                                                int* __restrict__ btot) {
    __shared__ int wtot[16];
    __shared__ int wexc[16];
    const int t = threadIdx.x;
    const int lane = t & 63;
    const int wd = t >> 6;
    const int i = blockIdx.x * 1024 + t;
    int v = (i < N_NODES) ? cnt[i] : 0;
    const int orig = v;
    #pragma unroll
    for (int off = 1; off < 64; off <<= 1) {
        int y = __shfl_up(v, off);
        if (lane >= off) v += y;
    }
    if (lane == 63) wtot[wd] = v;
    __syncthreads();
    if (t < 16) {
        int w = wtot[t];
        #pragma unroll
        for (int off = 1; off < 16; off <<= 1) {
            int y = __shfl_up(w, off);
            if (t >= off) w += y;
        }
        wexc[t] = w - wtot[t];
    }
    __syncthreads();
    if (i < N_NODES) ptr[i] = wexc[wd] + (v - orig);
    if (t == 0) btot[blockIdx.x] = wexc[15] + wtot[15];
}

__global__ __launch_bounds__(64) void k_scanB(int* __restrict__ btot,
                                              int* __restrict__ ptr) {
    const int t = threadIdx.x;
    int v = (t < 49) ? btot[t] : 0;
    const int orig = v;
    #pragma unroll
    for (int off = 1; off < 64; off <<= 1) {
        int y = __shfl_up(v, off);
        if (t >= off) v += y;
    }
    if (t < 49) btot[t] = v - orig;  // single wave: all loads precede stores
    if (t == 0) ptr[N_NODES] = E_EDGES;
}

__global__ __launch_bounds__(1024) void k_scanC(int* __restrict__ ptr,
                                                const int* __restrict__ btot) {
    const int i = blockIdx.x * 1024 + threadIdx.x;
    if (i < N_NODES) ptr[i] += btot[blockIdx.x];
}

// ---------- scatter: no atomics, 8 independent edges/thread ----------
__global__ __launch_bounds__(256) void k_scatter(const int* __restrict__ ei,
                                                 const int* __restrict__ rank,
                                                 const int* __restrict__ ptr,
                                                 int* __restrict__ srcidx) {
    const int gid = blockIdx.x * 256 + threadIdx.x;
    if (gid >= E_EDGES / 8) return;
    const int4 w0 = ((const int4*)ei)[2 * gid];
    const int4 w1 = ((const int4*)ei)[2 * gid + 1];
    const int4 c0 = ((const int4*)(ei + E_EDGES))[2 * gid];
    const int4 c1 = ((const int4*)(ei + E_EDGES))[2 * gid + 1];
    const int4 r0 = ((const int4*)rank)[2 * gid];
    const int4 r1 = ((const int4*)rank)[2 * gid + 1];
    const int p0 = ptr[c0.x] + r0.x;
    const int p1 = ptr[c0.y] + r0.y;
    const int p2 = ptr[c0.z] + r0.z;
    const int p3 = ptr[c0.w] + r0.w;
    const int p4 = ptr[c1.x] + r1.x;
    const int p5 = ptr[c1.y] + r1.y;
    const int p6 = ptr[c1.z] + r1.z;
    const int p7 = ptr[c1.w] + r1.w;
    srcidx[p0] = w0.x;
    srcidx[p1] = w0.y;
    srcidx[p2] = w0.z;
    srcidx[p3] = w0.w;
    srcidx[p4] = w1.x;
    srcidx[p5] = w1.y;
    srcidx[p6] = w1.z;
    srcidx[p7] = w1.w;
}

// ---------- h0 = relu(x@W0+b0) via MFMA, + layer-1 scores fused ----------
#define LROWS 128
#define KS 64
#define KP 72  // 64 + 8 pad

__global__ __launch_bounds__(256) void k_lin_mfma(
    const float* __restrict__ x, const u16* __restrict__ Wt,
    const float* __restrict__ b0, const float* __restrict__ aw1,
    u16* __restrict__ h, float* __restrict__ sa, float* __restrict__ sb) {
    __shared__ u16 As[LROWS][KP];
    __shared__ u16 Bs[HID][KP];
    const int t = threadIdx.x;
    const int lane = t & 63;
    const int w = t >> 6;
    const int sub = lane & 15;
    const int quad = lane >> 4;
    const int row0 = blockIdx.x * LROWS;

    floatx4 acc0[8], acc1[8];
    #pragma unroll
    for (int i = 0; i < 8; ++i) {
        acc0[i] = (floatx4){0.f, 0.f, 0.f, 0.f};
        acc1[i] = (floatx4){0.f, 0.f, 0.f, 0.f};
    }

    const int sr = t >> 1;
    const int sk = (t & 1) * 32;

    for (int k0 = 0; k0 < IN_DIM; k0 += KS) {
        {
            int gr = row0 + sr;
            if (gr > N_NODES - 1) gr = N_NODES - 1;
            const float* src = x + (size_t)gr * IN_DIM + k0 + sk;
            #pragma unroll
            for (int i = 0; i < 4; ++i) {
                float4 f0 = ((const float4*)src)[2 * i];
                float4 f1 = ((const float4*)src)[2 * i + 1];
                uint4 p;
                p.x = f2bf(f0.x) | ((unsigned)f2bf(f0.y) << 16);
                p.y = f2bf(f0.z) | ((unsigned)f2bf(f0.w) << 16);
                p.z = f2bf(f1.x) | ((unsigned)f2bf(f1.y) << 16);
                p.w = f2bf(f1.z) | ((unsigned)f2bf(f1.w) << 16);
                *(uint4*)&As[sr][sk + 8 * i] = p;
            }
            const u16* wsrc = Wt + sr * IN_DIM + k0 + sk;
            #pragma unroll
            for (int i = 0; i < 4; ++i)
                *(uint4*)&Bs[sr][sk + 8 * i] = ((const uint4*)wsrc)[i];
        }
        __syncthreads();
        #pragma unroll
        for (int kk = 0; kk < KS; kk += 32) {
            short8 a0 = *(const short8*)&As[w * 32 + sub][kk + quad * 8];
            short8 a1 = *(const short8*)&As[w * 32 + 16 + sub][kk + quad * 8];
            #pragma unroll
            for (int ct = 0; ct < 8; ++ct) {
                short8 bb = *(const short8*)&Bs[ct * 16 + sub][kk + quad * 8];
                acc0[ct] = __builtin_amdgcn_mfma_f32_16x16x32_bf16(a0, bb, acc0[ct], 0, 0, 0);
                acc1[ct] = __builtin_amdgcn_mfma_f32_16x16x32_bf16(a1, bb, acc1[ct], 0, 0, 0);
            }
        }
        __syncthreads();
    }

    float bias[8], w1c[8], w2c[8];
    #pragma unroll
    for (int ct = 0; ct < 8; ++ct) {
        const int col = ct * 16 + sub;
        bias[ct] = b0[col];
        w1c[ct] = aw1[col];
        w2c[ct] = aw1[HID + col];
    }
    float ps[2][4], pd[2][4];
    #pragma unroll
    for (int i = 0; i < 2; ++i)
        #pragma unroll
        for (int j = 0; j < 4; ++j) { ps[i][j] = 0.f; pd[i][j] = 0.f; }

    #pragma unroll
    for (int tile = 0; tile < 2; ++tile) {
        #pragma unroll
        for (int reg = 0; reg < 4; ++reg) {
            const int gr = row0 + w * 32 + tile * 16 + quad * 4 + reg;
            const bool ok = gr < N_NODES;
            #pragma unroll
            for (int ct = 0; ct < 8; ++ct) {
                floatx4 v = tile ? acc1[ct] : acc0[ct];
                const float val = fmaxf(v[reg] + bias[ct], 0.f);
                if (ok) h[(size_t)gr * HID + ct * 16 + sub] = f2bf(val);
                ps[tile][reg] += val * w1c[ct];
                pd[tile][reg] += val * w2c[ct];
            }
        }
    }
    #pragma unroll
    for (int tile = 0; tile < 2; ++tile) {
        #pragma unroll
        for (int reg = 0; reg < 4; ++reg) {
            float a = ps[tile][reg], d = pd[tile][reg];
            #pragma unroll
            for (int off = 1; off < 16; off <<= 1) {
                a += __shfl_xor(a, off);
                d += __shfl_xor(d, off);
            }
            if (sub == 0) {
                const int gr = row0 + w * 32 + tile * 16 + quad * 4 + reg;
                if (gr < N_NODES) { sa[gr] = a; sb[gr] = d; }
            }
        }
    }
}

// ---------- CSR aggregation (bf16 h) + eps-mix + relu + next-layer scores ----
// One QUARTER-WAVE (16 lanes) per node; lane sub owns channels 8*sub..8*sub+7.
// Inner loop unrolled 8 edges -> 8 independent 16B gathers in flight per lane.
__global__ __launch_bounds__(256) void k_agg(const u16* __restrict__ hin,
                                             const float* __restrict__ sa,
                                             const float* __restrict__ sb,
                                             const float* __restrict__ attb,
                                             const float* __restrict__ epsp,
                                             const int* __restrict__ ptr,
                                             const int* __restrict__ srcidx,
                                             u16* __restrict__ hout,
                                             const float* __restrict__ attw_next,
                                             float* __restrict__ sa_next,
                                             float* __restrict__ sb_next) {
    const int qid = threadIdx.x >> 4;   // 16 quarter-waves per block
    const int sub = threadIdx.x & 15;
    const int n = blockIdx.x * 16 + qid;
    if (n >= N_NODES) return;
    const float b = attb[0];
    const float sbn = sb[n];
    const int beg = ptr[n];
    const int end = ptr[n + 1];
    float acc[8];
    #pragma unroll
    for (int j = 0; j < 8; ++j) acc[j] = 0.f;

    int e = beg;
    for (; e + 8 <= end; e += 8) {
        int s[8];
        #pragma unroll
        for (int i = 0; i < 8; ++i) s[i] = srcidx[e + i];
        uint4 v[8];
        #pragma unroll
        for (int i = 0; i < 8; ++i)
            v[i] = *(const uint4*)(hin + (size_t)s[i] * HID + sub * 8);
        float al[8];
        #pragma unroll
        for (int i = 0; i < 8; ++i) al[i] = tanhf(sa[s[i]] + sbn + b);
        #pragma unroll
        for (int i = 0; i < 8; ++i) {
            float f[8];
            bf8_unpack(v[i], f);
            #pragma unroll
            for (int j = 0; j < 8; ++j) acc[j] += al[i] * f[j];
        }
    }
    for (; e < end; ++e) {
        const int s = srcidx[e];
        const float a = tanhf(sa[s] + sbn + b);
        const uint4 v = *(const uint4*)(hin + (size_t)s * HID + sub * 8);
        float f[8];
        bf8_unpack(v, f);
        #pragma unroll
        for (int j = 0; j < 8; ++j) acc[j] += a * f[j];
    }

    const float eps = epsp[0];
    const float om = 1.f - eps;
    const uint4 sv = *(const uint4*)(hin + (size_t)n * HID + sub * 8);
    float self[8], hv[8];
    bf8_unpack(sv, self);
    #pragma unroll
    for (int j = 0; j < 8; ++j)
        hv[j] = fmaxf(eps * self[j] + om * acc[j], 0.f);
    *(uint4*)(hout + (size_t)n * HID + sub * 8) = bf8_pack(hv);

    if (attw_next != nullptr) {
        float psum = 0.f, dsum = 0.f;
        #pragma unroll
        for (int j = 0; j < 8; ++j) {
            psum += hv[j] * attw_next[sub * 8 + j];
            dsum += hv[j] * attw_next[HID + sub * 8 + j];
        }
        #pragma unroll
        for (int off = 1; off < 16; off <<= 1) {
            psum += __shfl_xor(psum, off);
            dsum += __shfl_xor(dsum, off);
        }
        if (sub == 0) { sa_next[n] = psum; sb_next[n] = dsum; }
    }
}

// ---------- out = h2 @ Wc + bc via MFMA (h bf16, Wct bf16 pre-transposed) ----
__global__ __launch_bounds__(256) void k_out_mfma(const u16* __restrict__ h,
                                                  const u16* __restrict__ Wct,
                                                  const float* __restrict__ bc,
                                                  float* __restrict__ out) {
    const int t = threadIdx.x;
    const int lane = t & 63;
    const int w = t >> 6;
    const int sub = lane & 15;
    const int quad = lane >> 4;
    const int row0 = blockIdx.x * 128 + w * 32;

    floatx4 acc[2][4];
    #pragma unroll
    for (int i = 0; i < 2; ++i)
        #pragma unroll
        for (int j = 0; j < 4; ++j) acc[i][j] = (floatx4){0.f, 0.f, 0.f, 0.f};

    int r0 = row0 + sub;      if (r0 > N_NODES - 1) r0 = N_NODES - 1;
    int r1 = row0 + 16 + sub; if (r1 > N_NODES - 1) r1 = N_NODES - 1;

    #pragma unroll
    for (int ks = 0; ks < 4; ++ks) {
        const int ko = ks * 32 + quad * 8;
        short8 a0 = *(const short8*)(h + (size_t)r0 * HID + ko);
        short8 a1 = *(const short8*)(h + (size_t)r1 * HID + ko);
        #pragma unroll
        for (int ct = 0; ct < 4; ++ct) {
            short8 bb = *(const short8*)(Wct + (ct * 16 + sub) * HID + ko);
            acc[0][ct] = __builtin_amdgcn_mfma_f32_16x16x32_bf16(a0, bb, acc[0][ct], 0, 0, 0);
            acc[1][ct] = __builtin_amdgcn_mfma_f32_16x16x32_bf16(a1, bb, acc[1][ct], 0, 0, 0);
        }
    }

    #pragma unroll
    for (int ct = 0; ct < 4; ++ct) {
        const float bias = bc[ct * 16 + sub];
        #pragma unroll
        for (int tile = 0; tile < 2; ++tile) {
            #pragma unroll
            for (int reg = 0; reg < 4; ++reg) {
                const int gr = row0 + tile * 16 + quad * 4 + reg;
                if (gr < N_NODES)
                    out[(size_t)gr * OUT_DIM + ct * 16 + sub] = acc[tile][ct][reg] + bias;
            }
        }
    }
}

extern "C" void kernel_launch(void* const* d_in, const int* in_sizes, int n_in,
                              void* d_out, int out_size, void* d_ws, size_t ws_size,
                              hipStream_t stream) {
    const float* x   = (const float*)d_in[0];
    const int*   ei  = (const int*)d_in[1];
    const float* W0  = (const float*)d_in[2];
    const float* b0  = (const float*)d_in[3];
    const float* aw1 = (const float*)d_in[4];
    const float* ab1 = (const float*)d_in[5];
    const float* e1  = (const float*)d_in[6];
    const float* aw2 = (const float*)d_in[7];
    const float* ab2 = (const float*)d_in[8];
    const float* e2  = (const float*)d_in[9];
    const float* Wc  = (const float*)d_in[10];
    const float* bc  = (const float*)d_in[11];
    float* out = (float*)d_out;

    // workspace layout
    u16* hA  = (u16*)d_ws;                             // N*HID bf16
    u16* hB  = hA + (size_t)N_NODES * HID;             // N*HID bf16
    u16* Wt  = hB + (size_t)N_NODES * HID;             // 128*256 bf16
    u16* Wct = Wt + IN_DIM * HID;                      // 64*128 bf16
    float* sa1 = (float*)(Wct + HID * OUT_DIM);        // N
    float* sb1 = sa1 + N_NODES;
    float* sa2 = sb1 + N_NODES;
    float* sb2 = sa2 + N_NODES;
    int* cnt    = (int*)(sb2 + N_NODES);               // N
    int* ptr    = cnt + N_NODES;                       // N+1
    int* srcidx = ptr + N_NODES + 1;                   // E
    int* rank   = srcidx + E_EDGES;                    // E
    int* btot   = rank + E_EDGES;                      // 64

    hipMemsetAsync(cnt, 0, N_NODES * sizeof(int), stream);
    k_prep<<<(E_EDGES / 8 + 255) / 256, 256, 0, stream>>>(ei, cnt, rank, W0, Wt, Wc, Wct);
    k_scanA<<<(N_NODES + 1023) / 1024, 1024, 0, stream>>>(cnt, ptr, btot);
    k_scanB<<<1, 64, 0, stream>>>(btot, ptr);
    k_scanC<<<(N_NODES + 1023) / 1024, 1024, 0, stream>>>(ptr, btot);
    k_scatter<<<(E_EDGES / 8 + 255) / 256, 256, 0, stream>>>(ei, rank, ptr, srcidx);

    k_lin_mfma<<<(N_NODES + LROWS - 1) / LROWS, 256, 0, stream>>>(x, Wt, b0, aw1,
                                                                  hA, sa1, sb1);
    k_agg<<<(N_NODES + 15) / 16, 256, 0, stream>>>(hA, sa1, sb1, ab1, e1, ptr, srcidx,
                                                   hB, aw2, sa2, sb2);
    k_agg<<<(N_NODES + 15) / 16, 256, 0, stream>>>(hB, sa2, sb2, ab2, e2, ptr, srcidx,
                                                   hA, nullptr, nullptr, nullptr);
    k_out_mfma<<<(N_NODES + 127) / 128, 256, 0, stream>>>(hA, Wct, bc, out);
}